// Round 11
// baseline (170.329 us; speedup 1.0000x reference)
//
#include <hip/hip_runtime.h>

// BioNet recurrence: X <- mml_act(W @ X + X_bias), fixed point of a sparse
// contraction map (reference: extra steps past convergence are no-ops).
// R11: FULLY FUSED single persistent cooperative kernel.
//   phase 1: publish X1 = act(xbias) (needs no W) -> global barrier (slot 0)
//            (guards against garbage/NaN in x on the correctness call)
//   phase 2: each block sparsifies its own 32 W rows DIRECTLY INTO LDS
//            (one wave per 2 rows, ballot/popcount, pad to mult of 16 with
//            own-row weight-0 entries = exact no-ops). No global ELL.
//   phase 3: 8 unsynced async sweeps (vote can't pass this early; barrier
//            exists only for the quiesce vote)
//   phase 4: vote rounds of 4 sweeps (immutable per-round ctr slot, R7/R8)
//   phase 5: coalesced out-write via LDS transpose tile
// Single sc1 X buffer (L3-coherent, zero cache maintenance) throughout.

#define N_NODES 8192
#define BATCH   32
#define MAX_NNZ 64       // Poisson(16) row nnz; P(row > 64) ~ 1e-18
#define LEAK    0.01f
#define NBLK    256      // one block per CU (proven cooperative envelope)
#define TPB     1024     // 32 rows x 32 batch per block
#define RPB     32
#define TOL     2e-4f    // per-element quiesce tolerance
#define PRE_SWEEPS 8     // unsynced sweeps before first vote
#define K_SWEEPS 4       // sweeps per vote round
#define MAX_ROUNDS 28    // 8 + 28*4 = 120 sweeps = reference cap
#define CTR_STRIDE 32    // uints per counter slot (one 128 B line each)

// ---------------------------------------------------------------------------
__device__ __forceinline__ float mml_act(float x) {
  float fx = (x >= 0.0f) ? x : LEAK * x;
  return (fx < 0.5f) ? fx : (0.5f + 0.5f * (fx - 0.5f) / fx);
}

// Agent-scope relaxed (sc1): coherent at L3, no buffer_inv / buffer_wbl2.
__device__ __forceinline__ float coh_load(const float* p) {
  return __hip_atomic_load(const_cast<float*>(p), __ATOMIC_RELAXED,
                           __HIP_MEMORY_SCOPE_AGENT);
}
__device__ __forceinline__ unsigned coh_load_u(const unsigned* p) {
  return __hip_atomic_load(const_cast<unsigned*>(p), __ATOMIC_RELAXED,
                           __HIP_MEMORY_SCOPE_AGENT);
}
__device__ __forceinline__ void coh_store(float* p, float v) {
  __hip_atomic_store(p, v, __ATOMIC_RELAXED, __HIP_MEMORY_SCOPE_AGENT);
}

// ---------------------------------------------------------------------------
__global__ __launch_bounds__(TPB) void bionet_fused(
    const float4* __restrict__ W4, const float* __restrict__ Xfull,
    const float* __restrict__ bias, float* __restrict__ x,
    unsigned* __restrict__ ctr, float* __restrict__ out) {
  __shared__ float2 ell_lds[RPB * MAX_NNZ];  // 16 KiB (reused as out-tile)
  __shared__ int cnt_lds[RPB];
  __shared__ int s_allconv;

  const int tid = threadIdx.x;
  const int r0 = blockIdx.x * RPB;
  const int rl = tid >> 5;
  const int r = r0 + rl;
  const int b = tid & 31;
  const int idx = (r << 5) + b;

  // ---- phase 1: publish X1 = act(W@0 + xbias) = act(xbias); x needs no W --
  const float xbias = Xfull[(size_t)b * N_NODES + r] + bias[r];
  float xn = mml_act(xbias);
  coh_store(&x[idx], xn);

  // global barrier (slot 0): all x valid before ANY gather (correctness call
  // starts from arbitrary ws garbage -> must not be read).
  asm volatile("s_waitcnt vmcnt(0)" ::: "memory");
  __syncthreads();
  if (tid == 0) {
    unsigned* slot = &ctr[0];
    __hip_atomic_fetch_add(slot, 1u, __ATOMIC_RELAXED,
                           __HIP_MEMORY_SCOPE_AGENT);
    while ((coh_load_u(slot) & 0xFFFFu) < (unsigned)NBLK)
      __builtin_amdgcn_s_sleep(1);
  }
  __syncthreads();

  // ---- phase 2: sparsify own 32 rows into LDS (wave w -> rows 2w, 2w+1) ---
  {
    const int wave = tid >> 6;
    const int lane = tid & 63;
#pragma unroll 1
    for (int rr = 2 * wave; rr <= 2 * wave + 1; ++rr) {
      const float4* row = W4 + (size_t)(r0 + rr) * (N_NODES / 4);
      float2* o = &ell_lds[rr * MAX_NNZ];
      int base = 0;
#pragma unroll 1
      for (int it = 0; it < N_NODES / 256; ++it) {
        float4 v = row[it * 64 + lane];
#pragma unroll
        for (int j = 0; j < 4; ++j) {
          float w = (j == 0) ? v.x : (j == 1) ? v.y : (j == 2) ? v.z : v.w;
          bool nz = (w != 0.0f);
          unsigned long long m = __ballot(nz);
          if (nz) {
            int slot = base + (int)__popcll(m & ((1ull << lane) - 1ull));
            if (slot < MAX_NNZ)
              o[slot] = make_float2(
                  __int_as_float((it * 256 + lane * 4 + j) << 5), w);
          }
          base += (int)__popcll(m);
        }
      }
      int cnt = base < MAX_NNZ ? base : MAX_NNZ;
      int cntp = (cnt + 15) & ~15;
      if (cntp < 16) cntp = 16;
      if (cntp > MAX_NNZ) cntp = MAX_NNZ;
      if (lane < cntp - cnt)               // scattered own-row weight-0 pads
        o[cnt + lane] = make_float2(__int_as_float((r0 + rr) << 5), 0.0f);
      if (lane == 0) cnt_lds[rr] = cntp;
    }
  }
  __syncthreads();

  const int cnt = cnt_lds[rl];             // multiple of 16
  const float2* e = &ell_lds[rl * MAX_NNZ];

  // ---- phase 3: unsynced async sweeps (no vote possible this early) ------
#pragma unroll 1
  for (int k = 0; k < PRE_SWEEPS; ++k) {
    float acc = xbias;
    for (int i = 0; i < cnt; i += 16) {
#pragma unroll
      for (int j = 0; j < 16; ++j) {       // 16 coherent gathers in flight
        float2 w = e[i + j];
        acc = fmaf(w.y, coh_load(&x[__float_as_int(w.x) + b]), acc);
      }
    }
    xn = mml_act(acc);
    coh_store(&x[idx], xn);
  }

  // ---- phase 4: vote rounds (slots 1..MAX_ROUNDS) -------------------------
#pragma unroll 1
  for (int round = 1; round <= MAX_ROUNDS; ++round) {
    float delta = 0.0f;
#pragma unroll 1
    for (int k = 0; k < K_SWEEPS; ++k) {
      float acc = xbias;
      for (int i = 0; i < cnt; i += 16) {
#pragma unroll
        for (int j = 0; j < 16; ++j) {
          float2 w = e[i + j];
          acc = fmaf(w.y, coh_load(&x[__float_as_int(w.x) + b]), acc);
        }
      }
      float xnew = mml_act(acc);
      delta = fabsf(xnew - xn);
      xn = xnew;
      coh_store(&x[idx], xn);
    }

    asm volatile("s_waitcnt vmcnt(0)" ::: "memory");
    int blockconv = __syncthreads_and((int)(delta <= TOL));
    if (tid == 0) {
      unsigned* slot = &ctr[(size_t)round * CTR_STRIDE];
      __hip_atomic_fetch_add(slot, 1u | ((blockconv ? 0u : 1u) << 16),
                             __ATOMIC_RELAXED, __HIP_MEMORY_SCOPE_AGENT);
      unsigned v;
      while (((v = coh_load_u(slot)) & 0xFFFFu) < (unsigned)NBLK)
        __builtin_amdgcn_s_sleep(1);
      // slot immutable once full -> identical value at every block ->
      // uniform exit decision (deadlock-free by construction).
      s_allconv = ((v >> 16) == 0u);
    }
    __syncthreads();
    if (s_allconv) break;                  // global fixed point reached
  }

  // ---- phase 5: coalesced out-write via LDS transpose ---------------------
  float* tile = (float*)ell_lds;           // reuse: 32 x 33 floats = 4.2 KiB
  __syncthreads();                         // ELL reads done
  tile[rl * 33 + b] = xn;                  // tile[row][batch]
  __syncthreads();
  const int bb = tid >> 5;                 // batch this thread writes
  const int rc = tid & 31;                 // row-local column
  out[(size_t)bb * N_NODES + r0 + rc] = tile[rc * 33 + bb];  // 128 B/half-wave
}

// ---------------------------------------------------------------------------
extern "C" void kernel_launch(void* const* d_in, const int* in_sizes, int n_in,
                              void* d_out, int out_size, void* d_ws, size_t ws_size,
                              hipStream_t stream) {
  const float* Xfull = (const float*)d_in[0];   // [32][8192]
  const float* W     = (const float*)d_in[1];   // [8192][8192]
  const float* bias  = (const float*)d_in[2];   // [8192]
  float* out = (float*)d_out;                   // [32][8192]

  char* ws = (char*)d_ws;
  const size_t XB = (size_t)N_NODES * BATCH * sizeof(float);  // 1 MiB
  float*    x   = (float*)(ws);
  unsigned* ctr = (unsigned*)(ws + XB);         // (MAX_ROUNDS+1) slots

  // zero the vote counters (correctness call: ws is garbage; replays: stale)
  hipMemsetAsync(ctr, 0, (MAX_ROUNDS + 1) * CTR_STRIDE * sizeof(unsigned),
                 stream);

  const float4* W4 = (const float4*)W;
  void* args[] = {(void*)&W4, (void*)&Xfull, (void*)&bias,
                  (void*)&x, (void*)&ctr, (void*)&out};
  hipLaunchCooperativeKernel((const void*)bionet_fused,
                             dim3(NBLK), dim3(TPB), args, 0, stream);
}